// Round 2
// baseline (316.703 us; speedup 1.0000x reference)
//
#include <hip/hip_runtime.h>

#define RES   64
#define RES2  (RES*RES)        // 4096
#define RES3  (RES*RES*RES)    // 262144
#define NB    2
#define CIN   16
#define COUT  32
#define NVOX  (NB*RES3)        // 524288
#define NW    (27*CIN*COUT)    // 13824

// ws layout:
//   [0..15]                 : unsigned counters[2] (active, inactive) + pad
//   [16 .. 16+NVOX*4)       : int list[NVOX]  (actives from front, inactives from back)
//   [16+NVOX*4 .. +NW*4)    : float wt[9][16][3][32]  (dzdy, ci, dx, o)

// Kernel 1: weight transpose w[1][o][ci][kd][kh][kw] -> wt[dzdy][ci][dx][o],
// dzdy = kd*3+kh, dx = kw. Contiguous 96-float block per (dzdy,ci) so the
// conv kernel's weight reads are wave-uniform contiguous -> s_load_dwordx16.
// Also zero the compaction counters.
__global__ __launch_bounds__(256) void wtrans_kernel(
    const float* __restrict__ w, float* __restrict__ wt,
    unsigned int* __restrict__ counters) {
    if (blockIdx.x == 0 && threadIdx.x < 2) counters[threadIdx.x] = 0u;
    int i = blockIdx.x * 256 + threadIdx.x;
    if (i >= NW) return;
    int o    = i & 31;
    int r    = i >> 5;          // (dzdy*16+ci)*3+dx
    int dx   = r % 3;
    int r2   = r / 3;
    int ci   = r2 & 15;
    int dzdy = r2 >> 4;
    wt[i] = w[(o * CIN + ci) * 27 + dzdy * 3 + dx];
}

// Kernel 2: occupancy scan + order-preserving two-sided compaction.
// Actives packed from list[0] upward, inactives from list[NVOX-1] downward.
// No output writes here (sconv writes the zeros) -> this is a pure 32 MiB
// streaming read + 2 MiB write.
__global__ __launch_bounds__(256) void compact_kernel(
    const float* __restrict__ x, int* __restrict__ list,
    unsigned int* __restrict__ counters) {
    int v  = blockIdx.x * 256 + threadIdx.x;   // grid covers NVOX exactly
    int b  = v >> 18;
    int sp = v & (RES3 - 1);
    const float* xp = x + (size_t)b * CIN * RES3 + sp;
    bool act = false;
    #pragma unroll
    for (int ci = 0; ci < CIN; ++ci) act = act || (xp[ci * RES3] != 0.0f);

    unsigned long long m = __ballot(act);
    int lane = threadIdx.x & 63;
    int wid  = threadIdx.x >> 6;
    __shared__ unsigned wa[4], wbase_a[4], wbase_i[4];
    if (lane == 0) wa[wid] = (unsigned)__popcll(m);
    __syncthreads();
    if (threadIdx.x == 0) {
        unsigned ta = wa[0] + wa[1] + wa[2] + wa[3];
        unsigned ba = atomicAdd(&counters[0], ta);
        unsigned bi = atomicAdd(&counters[1], 256u - ta);
        unsigned ca = 0, ci_ = 0;
        #pragma unroll
        for (int k = 0; k < 4; ++k) {
            wbase_a[k] = ba + ca;
            wbase_i[k] = bi + ci_;
            ca  += wa[k];
            ci_ += 64u - wa[k];
        }
    }
    __syncthreads();
    unsigned long long lt = (1ull << lane) - 1ull;
    if (act) {
        unsigned pos = wbase_a[wid] + (unsigned)__popcll(m & lt);
        list[pos] = v;
    } else {
        unsigned pos = wbase_i[wid] + (unsigned)__popcll((~m) & lt);
        list[NVOX - 1 - pos] = v;
    }
}

// Kernel 3: conv at active voxels (i < n), zero-fill at inactive (i >= n).
// Weights read via wave-uniform addresses -> scalar loads into SGPRs;
// acc[32] stays in VGPRs (outer loops NOT unrolled, only the 96-FMA body).
__global__ __launch_bounds__(256) void sconv_kernel(
    const float* __restrict__ x, const float* __restrict__ wt,
    const int* __restrict__ list, const unsigned int* __restrict__ counters,
    float* __restrict__ out) {
    unsigned int n = counters[0];
    // XCD-aware swizzle: 2048 blocks, 8 XCDs -> 256 contiguous chunks each.
    int bid  = blockIdx.x;
    int sbid = (bid & 7) * 256 + (bid >> 3);
    unsigned int i = (unsigned)sbid * 256u + threadIdx.x;

    if (i >= (unsigned)NVOX) return;  // safety (grid == NVOX/256 exactly)

    if (i >= n) {
        // inactive voxel: write the 32 output zeros
        int v  = list[NVOX - 1 - (int)(i - n)];
        int b  = v >> 18;
        int sp = v & (RES3 - 1);
        float* ob = out + (size_t)b * COUT * RES3 + sp;
        #pragma unroll
        for (int o = 0; o < COUT; ++o) ob[o * RES3] = 0.0f;
        return;
    }

    int v  = list[i];
    int b  = v >> 18;
    int sp = v & (RES3 - 1);
    int z  = sp >> 12;
    int y  = (sp >> 6) & 63;
    int xw = sp & 63;

    const float* xb = x + (size_t)b * CIN * RES3;
    const bool lok = (xw > 0), rok = (xw < RES - 1);
    const int offL = lok ? -1 : 0;
    const int offR = rok ?  1 : 0;

    float acc[COUT];
    #pragma unroll
    for (int o = 0; o < COUT; ++o) acc[o] = 0.0f;

    #pragma unroll 1
    for (int dzdy = 0; dzdy < 9; ++dzdy) {
        int nz = z + (dzdy / 3) - 1;
        int ny = y + (dzdy % 3) - 1;
        bool vzy = ((unsigned)nz < (unsigned)RES) && ((unsigned)ny < (unsigned)RES);
        int nzc = min(max(nz, 0), RES - 1);
        int nyc = min(max(ny, 0), RES - 1);
        const float* xrow = xb + nzc * RES2 + nyc * RES + xw;
        const float* wrow = wt + dzdy * (CIN * 96);
        const bool vL = vzy && lok, vR = vzy && rok;

        #pragma unroll 1
        for (int ci = 0; ci < CIN; ++ci) {
            const float* xp = xrow + ci * RES3;
            float x0 = xp[offL];
            float x1 = xp[0];
            float x2 = xp[offR];
            x0 = vL  ? x0 : 0.0f;
            x1 = vzy ? x1 : 0.0f;
            x2 = vR  ? x2 : 0.0f;
            const float* wr = wrow + ci * 96;   // wave-uniform -> SGPR loads
            #pragma unroll
            for (int o = 0; o < COUT; ++o) {
                float a = acc[o];
                a = fmaf(x0, wr[o],      a);   // dx = -1 (kw=0)
                a = fmaf(x1, wr[32 + o], a);   // dx =  0 (kw=1)
                a = fmaf(x2, wr[64 + o], a);   // dx = +1 (kw=2)
                acc[o] = a;
            }
        }
    }

    float* ob = out + (size_t)b * COUT * RES3 + sp;
    #pragma unroll
    for (int o = 0; o < COUT; ++o) ob[o * RES3] = acc[o];
}

extern "C" void kernel_launch(void* const* d_in, const int* in_sizes, int n_in,
                              void* d_out, int out_size, void* d_ws, size_t ws_size,
                              hipStream_t stream) {
    const float* x = (const float*)d_in[0];   // [2,16,64,64,64]
    const float* w = (const float*)d_in[1];   // [1,32,16,3,3,3]
    float* out = (float*)d_out;               // [2,32,64,64,64]

    unsigned int* counters = (unsigned int*)d_ws;
    int*   list = (int*)((char*)d_ws + 16);
    float* wt   = (float*)((char*)d_ws + 16 + (size_t)NVOX * 4);

    wtrans_kernel<<<(NW + 255) / 256, 256, 0, stream>>>(w, wt, counters);
    compact_kernel<<<NVOX / 256, 256, 0, stream>>>(x, list, counters);
    sconv_kernel<<<NVOX / 256, 256, 0, stream>>>(x, wt, list, counters, out);
}

// Round 3
// 310.388 us; speedup vs baseline: 1.0203x; 1.0203x over previous
//
#include <hip/hip_runtime.h>

#define RES   64
#define RES2  (RES*RES)        // 4096
#define RES3  (RES*RES*RES)    // 262144
#define NB    2
#define CIN   16
#define COUT  32
#define NVOX  (NB*RES3)        // 524288
#define NW    (27*CIN*COUT)    // 13824

// ws layout (byte offsets):
//   0                     : unsigned counters[4]           (16 B)
//   16                    : int   list[NVOX]               (2 MiB)  r -> v
//   16+4*NVOX             : int   pos [NVOX]               (2 MiB)  v -> r (or -1)
//   16+8*NVOX             : float wt[9][16][3][32]         (54 KiB)
//   16+8*NVOX+4*NW        : float cmp[cap][32]             (cap from ws_size)

// ---- Kernel 1: weight transpose + zero counters --------------------------
__global__ __launch_bounds__(256) void wtrans_kernel(
    const float* __restrict__ w, float* __restrict__ wt,
    unsigned int* __restrict__ counters) {
    if (blockIdx.x == 0 && threadIdx.x < 4) counters[threadIdx.x] = 0u;
    int i = blockIdx.x * 256 + threadIdx.x;
    if (i >= NW) return;
    int o    = i & 31;
    int r    = i >> 5;          // (dzdy*16+ci)*3+dx
    int dx   = r % 3;
    int r2   = r / 3;
    int ci   = r2 & 15;
    int dzdy = r2 >> 4;
    wt[i] = w[(o * CIN + ci) * 27 + dzdy * 3 + dx];
}

// ---- Kernel 2: occupancy + compaction (list r->v, pos v->r) --------------
__global__ __launch_bounds__(256) void compact_kernel(
    const float* __restrict__ x, int* __restrict__ list, int* __restrict__ pos,
    unsigned int* __restrict__ counters) {
    int v  = blockIdx.x * 256 + threadIdx.x;   // grid covers NVOX exactly
    int b  = v >> 18;
    int sp = v & (RES3 - 1);
    const float* xp = x + (size_t)b * CIN * RES3 + sp;
    bool act = false;
    #pragma unroll
    for (int c = 0; c < CIN; ++c) act = act || (xp[c * RES3] != 0.0f);

    unsigned long long m = __ballot(act);
    int lane = threadIdx.x & 63;
    int wid  = threadIdx.x >> 6;
    __shared__ unsigned wc[4], wb[4];
    if (lane == 0) wc[wid] = (unsigned)__popcll(m);
    __syncthreads();
    if (threadIdx.x == 0) {
        unsigned t = wc[0] + wc[1] + wc[2] + wc[3];
        unsigned base = atomicAdd(&counters[0], t);
        unsigned s = 0;
        #pragma unroll
        for (int k = 0; k < 4; ++k) { wb[k] = base + s; s += wc[k]; }
    }
    __syncthreads();
    int r = -1;
    if (act) {
        r = (int)(wb[wid] + (unsigned)__popcll(m & ((1ull << lane) - 1ull)));
        list[r] = v;
    }
    pos[v] = r;   // dense coalesced 2 MiB write
}

// ---- Kernel 3: conv on compacted actives; streaming write to cmp ---------
__global__ __launch_bounds__(256, 3) void sconv_kernel(
    const float* __restrict__ x, const float* __restrict__ wt,
    const int* __restrict__ list, const unsigned int* __restrict__ counters,
    float* __restrict__ cmp, float* __restrict__ out, int cap) {
    unsigned int n = counters[0];
    // XCD swizzle: 2048 blocks -> 8 chunks of 256 contiguous sbids per XCD
    int bid  = blockIdx.x;
    int sbid = (bid & 7) * 256 + (bid >> 3);
    unsigned int i = (unsigned)sbid * 256u + threadIdx.x;
    if (i >= n) return;

    int v  = list[i];
    int b  = v >> 18;
    int sp = v & (RES3 - 1);
    int z  = sp >> 12;
    int y  = (sp >> 6) & 63;
    int xw = sp & 63;

    const float* xb = x + (size_t)b * CIN * RES3;
    const bool lok = (xw > 0), rok = (xw < RES - 1);
    const int offL = lok ? -1 : 0;
    const int offR = rok ?  1 : 0;

    float acc[COUT];
    #pragma unroll
    for (int o = 0; o < COUT; ++o) acc[o] = 0.0f;

    #pragma unroll 1
    for (int dzdy = 0; dzdy < 9; ++dzdy) {
        int kd = dzdy / 3;
        int kh = dzdy - kd * 3;
        int nz = z + kd - 1;
        int ny = y + kh - 1;
        bool vzy = ((unsigned)nz < (unsigned)RES) && ((unsigned)ny < (unsigned)RES);
        int nzc = min(max(nz, 0), RES - 1);
        int nyc = min(max(ny, 0), RES - 1);
        const float* xrow = xb + nzc * RES2 + nyc * RES + xw;
        const float* wrow = wt + dzdy * (CIN * 96);   // uniform -> s_load
        const bool vL = vzy && lok, vR = vzy && rok;

        #pragma unroll 2
        for (int ci = 0; ci < CIN; ++ci) {
            const float* xp = xrow + ci * RES3;
            float x0 = xp[offL];
            float x1 = xp[0];
            float x2 = xp[offR];
            x0 = vL  ? x0 : 0.0f;
            x1 = vzy ? x1 : 0.0f;
            x2 = vR  ? x2 : 0.0f;
            const float* wp = wrow + ci * 96;
            #pragma unroll
            for (int o = 0; o < COUT; ++o)
                acc[o] = fmaf(x0, wp[o],
                         fmaf(x1, wp[32 + o],
                         fmaf(x2, wp[64 + o], acc[o])));
        }
    }

    if ((int)i < cap) {
        // streaming, 128 B contiguous per thread
        float4* cp = (float4*)(cmp + (size_t)i * COUT);
        #pragma unroll
        for (int q = 0; q < 8; ++q)
            cp[q] = make_float4(acc[4*q], acc[4*q+1], acc[4*q+2], acc[4*q+3]);
    } else {
        // overflow fallback (never hit at 30% occupancy unless ws is tiny)
        float* ob = out + (size_t)b * COUT * RES3 + sp;
        #pragma unroll
        for (int o = 0; o < COUT; ++o) ob[o * RES3] = acc[o];
    }
}

// ---- Kernel 4: dense scatter — every output line written exactly once ----
__global__ __launch_bounds__(256) void scatter_kernel(
    const float* __restrict__ cmp, const int* __restrict__ pos,
    float* __restrict__ out, int cap) {
    int v = blockIdx.x * 256 + threadIdx.x;
    int r = pos[v];
    if (r >= cap) return;   // sconv already wrote these directly
    int b  = v >> 18;
    int sp = v & (RES3 - 1);
    float vals[COUT];
    if (r >= 0) {
        const float4* cp = (const float4*)(cmp + (size_t)r * COUT);
        #pragma unroll
        for (int q = 0; q < 8; ++q) {
            float4 t = cp[q];
            vals[4*q] = t.x; vals[4*q+1] = t.y; vals[4*q+2] = t.z; vals[4*q+3] = t.w;
        }
    } else {
        #pragma unroll
        for (int o = 0; o < COUT; ++o) vals[o] = 0.0f;
    }
    float* ob = out + (size_t)b * COUT * RES3 + sp;
    #pragma unroll
    for (int o = 0; o < COUT; ++o) ob[o * RES3] = vals[o];   // dense, coalesced
}

extern "C" void kernel_launch(void* const* d_in, const int* in_sizes, int n_in,
                              void* d_out, int out_size, void* d_ws, size_t ws_size,
                              hipStream_t stream) {
    const float* x = (const float*)d_in[0];   // [2,16,64,64,64]
    const float* w = (const float*)d_in[1];   // [1,32,16,3,3,3]
    float* out = (float*)d_out;               // [2,32,64,64,64]

    unsigned int* counters = (unsigned int*)d_ws;
    int*   list = (int*)((char*)d_ws + 16);
    int*   pos  = (int*)((char*)d_ws + 16 + (size_t)NVOX * 4);
    float* wt   = (float*)((char*)d_ws + 16 + (size_t)NVOX * 8);
    const size_t FIXED = 16 + (size_t)NVOX * 8 + (size_t)NW * 4;
    float* cmp  = (float*)((char*)d_ws + FIXED);

    long cap_l = 0;
    if (ws_size > FIXED) cap_l = (long)((ws_size - FIXED) / (COUT * 4));
    if (cap_l > NVOX) cap_l = NVOX;
    int cap = (int)cap_l;   // constant across calls -> graph-safe

    wtrans_kernel <<<(NW + 255) / 256, 256, 0, stream>>>(w, wt, counters);
    compact_kernel<<<NVOX / 256,      256, 0, stream>>>(x, list, pos, counters);
    sconv_kernel  <<<NVOX / 256,      256, 0, stream>>>(x, wt, list, counters, cmp, out, cap);
    scatter_kernel<<<NVOX / 256,      256, 0, stream>>>(cmp, pos, out, cap);
}

// Round 5
// 132.714 us; speedup vs baseline: 2.3864x; 2.3388x over previous
//
#include <hip/hip_runtime.h>

#define RES   64
#define RES2  4096
#define RES3  262144
#define CIN   16
#define COUT  32
#define TZ    4
#define TY    4
// LDS: xt[6][6][68][16] halfs (x-extent 66 used, 68 stride) + wa[27][32][16] halfs
#define XT_HALFS (6*6*68*16)        // 39168
#define XT_BYTES (XT_HALFS*2)       // 78336
#define WA_HALFS (27*32*16)         // 13824
#define WA_BYTES (WA_HALFS*2)       // 27648
#define LDS_BYTES (XT_BYTES + WA_BYTES)  // 105984

typedef _Float16 f16x8 __attribute__((ext_vector_type(8)));
typedef float   f32x16 __attribute__((ext_vector_type(16)));

static __device__ __forceinline__ unsigned int pack2(float v0, float v1) {
    _Float16 h0 = (_Float16)v0;
    _Float16 h1 = (_Float16)v1;
    unsigned short u0 = __builtin_bit_cast(unsigned short, h0);
    unsigned short u1 = __builtin_bit_cast(unsigned short, h1);
    return (unsigned int)u0 | ((unsigned int)u1 << 16);
}

// ---- Kernel 1: weights fp32 [o][ci][27] -> fp16 wa-layout [tap][o][ci] ----
__global__ __launch_bounds__(1024) void wtrans_kernel(
    const float* __restrict__ w, _Float16* __restrict__ wtg) {
    int i = blockIdx.x * 1024 + threadIdx.x;
    if (i >= WA_HALFS) return;
    int tap = i >> 9;          // 0..26
    int o   = (i >> 4) & 31;
    int ci  = i & 15;
    wtg[i] = (_Float16)w[(o * CIN + ci) * 27 + tap];
}

// ---- Kernel 2: dense MFMA conv over a 4x4x64 tile, occupancy-masked ------
__global__ __launch_bounds__(1024) void conv_kernel(
    const float* __restrict__ x, const _Float16* __restrict__ wtg,
    float* __restrict__ out) {

    extern __shared__ char smem[];
    _Float16* xt = (_Float16*)smem;               // [iz][iy][ix(68)][ci]
    _Float16* wa = (_Float16*)(smem + XT_BYTES);  // [tap][o][ci]

    // 512 blocks -> bijective XCD swizzle (512 % 8 == 0)
    int bid = blockIdx.x;
    int sb  = (bid & 7) * 64 + (bid >> 3);
    int b   = sb >> 8;              // batch 0..1
    int zt0 = (sb >> 4) & 15;       // z-tile
    int yt0 = sb & 15;              // y-tile
    int z0 = zt0 * TZ, y0 = yt0 * TY;

    int tid  = threadIdx.x;
    int lane = tid & 63;
    int wv   = tid >> 6;            // wave 0..15
    int hi   = lane >> 5;
    int l31  = lane & 31;

    // ---- stage weights (coalesced u32 copy) ----
    {
        const unsigned int* src = (const unsigned int*)wtg;
        unsigned int* dst = (unsigned int*)wa;
        for (int j = tid; j < WA_BYTES / 4; j += 1024) dst[j] = src[j];
    }

    // ---- stage x tile: rows (iz,iy) = 36; fp32 -> fp16, ci innermost ----
    for (int r = wv; r < 36; r += 16) {
        int iz = r / 6, iy = r % 6;
        int gz = z0 + iz - 1, gy = y0 + iy - 1;
        bool rowok = ((unsigned)gz < RES) && ((unsigned)gy < RES);
        const float* rp = x + (size_t)b * CIN * RES3 + gz * RES2 + gy * RES;

        int gx = lane - 1;                         // ix = lane (0..63)
        bool lok = rowok && ((unsigned)gx < RES);
        unsigned int pk[8];
        #pragma unroll
        for (int cp = 0; cp < 8; ++cp) {
            float v0 = lok ? rp[(2 * cp    ) * RES3 + gx] : 0.0f;
            float v1 = lok ? rp[(2 * cp + 1) * RES3 + gx] : 0.0f;
            pk[cp] = pack2(v0, v1);
        }
        uint4* dst = (uint4*)(xt + r * 1088 + lane * 16);
        dst[0] = make_uint4(pk[0], pk[1], pk[2], pk[3]);
        dst[1] = make_uint4(pk[4], pk[5], pk[6], pk[7]);

        if (lane < 2) {                            // ix = 64, 65
            int ix2 = 64 + lane;
            int gx2 = ix2 - 1;                     // 63 (ok), 64 (OOB)
            bool ok2 = rowok && (gx2 < RES);
            unsigned int pk2[8];
            #pragma unroll
            for (int cp = 0; cp < 8; ++cp) {
                float v0 = ok2 ? rp[(2 * cp    ) * RES3 + gx2] : 0.0f;
                float v1 = ok2 ? rp[(2 * cp + 1) * RES3 + gx2] : 0.0f;
                pk2[cp] = pack2(v0, v1);
            }
            uint4* d2 = (uint4*)(xt + r * 1088 + ix2 * 16);
            d2[0] = make_uint4(pk2[0], pk2[1], pk2[2], pk2[3]);
            d2[1] = make_uint4(pk2[4], pk2[5], pk2[6], pk2[7]);
        }
    }
    __syncthreads();

    // ---- wave -> column tiles: ctid = q*16 + wv; (oz,oy,xh) from ctid ----
    int oy  = (wv >> 1) & 3;
    int xh  = wv & 1;
    int ozA = (wv >> 3);        // q=0 -> oz 0..1
    int ozB = ozA + 2;          // q=1 -> oz 2..3

    int lpart = l31 * 32 + hi * 16;
    int baseA = ((ozA + 1) * 6 + oy + 1) * 2176 + (xh * 32 + 1) * 32 + lpart;
    int baseB = ((ozB + 1) * 6 + oy + 1) * 2176 + (xh * 32 + 1) * 32 + lpart;
    const char* xtb = (const char*)xt;
    const char* wab = (const char*)wa;

    f32x16 acc0 = {};
    f32x16 acc1 = {};

    #pragma unroll
    for (int tap = 0; tap < 27; ++tap) {
        const int dz  = tap / 9 - 1;
        const int dy  = (tap / 3) % 3 - 1;
        const int dxx = tap % 3 - 1;
        const int toff = (dz * 6 + dy) * 2176 + dxx * 32;
        f16x8 afrag = *(const f16x8*)(wab + tap * 1024 + lpart);
        f16x8 b0 = *(const f16x8*)(xtb + baseA + toff);
        f16x8 b1 = *(const f16x8*)(xtb + baseB + toff);
        acc0 = __builtin_amdgcn_mfma_f32_32x32x16_f16(afrag, b0, acc0, 0, 0, 0);
        acc1 = __builtin_amdgcn_mfma_f32_32x32x16_f16(afrag, b1, acc1, 0, 0, 0);
    }

    // ---- epilogue: occupancy mask from staged fp16 tile, masked store ----
    // zero check must treat 0x0000 and 0x8000 (-0.0f from normal*0) as zero
    {
        const uint4* vv = (const uint4*)(xtb + ((ozA + 1) * 6 + oy + 1) * 2176
                                             + (xh * 32 + 1 + l31) * 32);
        uint4 a = vv[0], c = vv[1];
        unsigned int m = (a.x | a.y | a.z | a.w | c.x | c.y | c.z | c.w) & 0x7FFF7FFFu;
        bool occ = (m != 0u);
        size_t vaddr = (size_t)(z0 + ozA) * RES2 + (y0 + oy) * RES + xh * 32 + l31;
        #pragma unroll
        for (int r = 0; r < 16; ++r) {
            int o = (r & 3) + 8 * (r >> 2) + 4 * hi;
            float val = occ ? acc0[r] : 0.0f;
            out[((size_t)(b * COUT + o) << 18) + vaddr] = val;
        }
    }
    {
        const uint4* vv = (const uint4*)(xtb + ((ozB + 1) * 6 + oy + 1) * 2176
                                             + (xh * 32 + 1 + l31) * 32);
        uint4 a = vv[0], c = vv[1];
        unsigned int m = (a.x | a.y | a.z | a.w | c.x | c.y | c.z | c.w) & 0x7FFF7FFFu;
        bool occ = (m != 0u);
        size_t vaddr = (size_t)(z0 + ozB) * RES2 + (y0 + oy) * RES + xh * 32 + l31;
        #pragma unroll
        for (int r = 0; r < 16; ++r) {
            int o = (r & 3) + 8 * (r >> 2) + 4 * hi;
            float val = occ ? acc1[r] : 0.0f;
            out[((size_t)(b * COUT + o) << 18) + vaddr] = val;
        }
    }
}

extern "C" void kernel_launch(void* const* d_in, const int* in_sizes, int n_in,
                              void* d_out, int out_size, void* d_ws, size_t ws_size,
                              hipStream_t stream) {
    const float* x = (const float*)d_in[0];   // [2,16,64,64,64]
    const float* w = (const float*)d_in[1];   // [1,32,16,3,3,3]
    float* out = (float*)d_out;               // [2,32,64,64,64]

    _Float16* wtg = (_Float16*)d_ws;          // 27648 B

    (void)hipFuncSetAttribute(reinterpret_cast<const void*>(conv_kernel),
                              hipFuncAttributeMaxDynamicSharedMemorySize, LDS_BYTES);

    wtrans_kernel<<<(WA_HALFS + 1023) / 1024, 1024, 0, stream>>>(w, wtg);
    conv_kernel<<<512, 1024, LDS_BYTES, stream>>>(x, wtg, out);
}

// Round 6
// 111.816 us; speedup vs baseline: 2.8323x; 1.1869x over previous
//
#include <hip/hip_runtime.h>

#define RES   64
#define RES2  4096
#define RES3  262144
#define CIN   16
#define COUT  32

// Padded fp16 tensor in ws: [b][z1:66][y1:66][hi:2][s:68][c8:8] halfs.
// z1=z+1, y1=y+1, s=x+1; out-of-range positions are stored as 0 -> conv
// staging has NO bounds checks.
#define PZ 66
#define PY 66
#define ROWB  1088                    // bytes of one (hi) row: 68*16
#define PROWB 2176                    // bytes per (b,z1,y1)
#define XH16_BYTES (2*PZ*PY*PROWB)    // 18,957,312
#define NCHUNK (XH16_BYTES/16)        // 1,184,832 uint4 chunks
#define WTG_OFF ((XH16_BYTES + 255) & ~255)
#define NWH (27*CIN*COUT)             // 13824 weight halfs

// conv tile: 2(z) x 4(y) x 64(x), 512 threads (8 waves), 2 ctiles/wave
#define TZ 2
#define TY 4
#define XT_BYTES (4*6*PROWB)          // 4 z-slabs * 6 y * 2176 = 52224
#define WA_BYTES (NWH*2)              // 27648
#define LDS_BYTES (XT_BYTES + WA_BYTES)  // 79872 -> 2 blocks/CU

typedef _Float16 f16x8 __attribute__((ext_vector_type(8)));
typedef float   f32x16 __attribute__((ext_vector_type(16)));

static __device__ __forceinline__ unsigned int pack2(float v0, float v1) {
    _Float16 h0 = (_Float16)v0;
    _Float16 h1 = (_Float16)v1;
    unsigned short u0 = __builtin_bit_cast(unsigned short, h0);
    unsigned short u1 = __builtin_bit_cast(unsigned short, h1);
    return (unsigned int)u0 | ((unsigned int)u1 << 16);
}

typedef __attribute__((address_space(1))) const unsigned int gu32;
typedef __attribute__((address_space(3))) unsigned int lu32;
static __device__ __forceinline__ void glds16(const void* g, void* l) {
    __builtin_amdgcn_global_load_lds((gu32*)g, (lu32*)l, 16, 0, 0);
}

// ---- Kernel 1: weights fp32 [o][ci][27] -> fp16 [tap][hi][o][c8] ---------
__global__ __launch_bounds__(256) void wtrans_kernel(
    const float* __restrict__ w, _Float16* __restrict__ wtg) {
    int i = blockIdx.x * 256 + threadIdx.x;
    if (i >= NWH) return;
    int tap = i >> 9;
    int hi  = (i >> 8) & 1;
    int o   = (i >> 3) & 31;
    int c   = i & 7;
    int ci  = hi * 8 + c;
    wtg[i] = (_Float16)w[(o * CIN + ci) * 27 + tap];
}

// ---- Kernel 2: x fp32 -> padded fp16 tensor ------------------------------
__global__ __launch_bounds__(256) void xcvt_kernel(
    const float* __restrict__ x, uint4* __restrict__ xh16) {
    for (int idx = blockIdx.x * 256 + threadIdx.x; idx < NCHUNK;
         idx += 2048 * 256) {
        int row = idx / 136;          // (b,z1,y1)
        int rem = idx - row * 136;
        int hi  = rem / 68;
        int s   = rem - hi * 68;
        int y1  = row % 66;
        int t   = row / 66;
        int z1  = t % 66;
        int b   = t / 66;

        uint4 val = make_uint4(0u, 0u, 0u, 0u);
        if (z1 >= 1 && z1 <= 64 && y1 >= 1 && y1 <= 64 && s >= 1 && s <= 64) {
            const float* sp = x + ((size_t)(b * CIN + hi * 8)) * RES3
                                + (z1 - 1) * RES2 + (y1 - 1) * RES + (s - 1);
            float f0 = sp[0 * RES3], f1 = sp[1 * RES3];
            float f2 = sp[2 * RES3], f3 = sp[3 * RES3];
            float f4 = sp[4 * RES3], f5 = sp[5 * RES3];
            float f6 = sp[6 * RES3], f7 = sp[7 * RES3];
            val.x = pack2(f0, f1);
            val.y = pack2(f2, f3);
            val.z = pack2(f4, f5);
            val.w = pack2(f6, f7);
        }
        xh16[idx] = val;
    }
}

// ---- Kernel 3: MFMA conv, 2x4x64 tile, 8 waves, 2 resident blocks/CU -----
__global__ __launch_bounds__(512, 4) void conv_kernel(
    const char* __restrict__ xh16b, const _Float16* __restrict__ wtg,
    float* __restrict__ out) {

    extern __shared__ char smem[];
    char* xt = smem;                  // [R:48][68][16B]  R=(iz*6+iy)*2+hi
    char* wa = smem + XT_BYTES;       // [tap][hi][32 o][16B]

    // 1024 blocks, bijective XCD swizzle
    int bid = blockIdx.x;
    int sb  = (bid & 7) * 128 + (bid >> 3);
    int b   = sb >> 9;
    int zt  = (sb >> 4) & 31;
    int yt  = sb & 15;
    int z0 = zt * TZ, y0 = yt * TY;

    int tid  = threadIdx.x;
    int lane = tid & 63;
    int wv   = tid >> 6;              // 0..7
    int hi   = lane >> 5;
    int l31  = lane & 31;

    // ---- stage weights via global_load_lds: 27 rows of 1024 B ----
    for (int j = wv; j < 27; j += 8) {
        glds16((const char*)wtg + j * 1024 + lane * 16, wa + j * 1024);
    }
    // ---- stage x tile: 48 rows of 1088 B, no bounds checks ----
    #pragma unroll
    for (int j = 0; j < 6; ++j) {
        int R   = wv * 6 + j;         // 0..47
        int iz  = R / 12;
        int rm  = R - iz * 12;
        int iy  = rm >> 1;
        int hh  = rm & 1;
        const char* srow = xh16b +
            ((((size_t)b * PZ + (z0 + iz)) * PY + (y0 + iy)) * 2 + hh) * (size_t)ROWB;
        char* drow = xt + R * ROWB;
        glds16(srow + lane * 16, drow);
        if (lane < 4) glds16(srow + 1024 + lane * 16, drow + 1024);
    }
    __syncthreads();

    // ---- wave -> 2 column tiles: (oz=0, acc0) and (oz=1, acc1) ----
    int oy = (wv >> 1) & 3;
    int xh = wv & 1;

    const int b_lane = hi * ROWB + (xh * 32 + 1 + l31) * 16;
    const int a_lane = hi * 512 + l31 * 16;

    f32x16 acc0 = {};
    f32x16 acc1 = {};

    #pragma unroll
    for (int tap = 0; tap < 27; ++tap) {
        const int dz  = tap / 9 - 1;
        const int dy  = (tap / 3) % 3 - 1;
        const int dxx = tap % 3 - 1;
        // acc0 rows: iz = 1+dz; acc1: iz = 2+dz (delta = 12 rows)
        const int u0 = (((1 + dz) * 6 + (oy + 1 + dy)) * 2) * ROWB + dxx * 16;
        f16x8 af = *(const f16x8*)(wa + tap * 1024 + a_lane);
        f16x8 b0 = *(const f16x8*)(xt + u0 + b_lane);
        f16x8 b1 = *(const f16x8*)(xt + u0 + 12 * ROWB + b_lane);
        acc0 = __builtin_amdgcn_mfma_f32_32x32x16_f16(af, b0, acc0, 0, 0, 0);
        acc1 = __builtin_amdgcn_mfma_f32_32x32x16_f16(af, b1, acc1, 0, 0, 0);
    }

    // ---- epilogue: occupancy from staged fp16 (&0x7FFF kills -0.0) ----
    const int ixb = (xh * 32 + 1 + l31) * 16;
    #pragma unroll
    for (int oz = 0; oz < 2; ++oz) {
        int R = (((oz + 1) * 6) + (oy + 1)) * 2;
        const uint4 a = *(const uint4*)(xt + R * ROWB + ixb);
        const uint4 c = *(const uint4*)(xt + (R + 1) * ROWB + ixb);
        unsigned m = (a.x | a.y | a.z | a.w | c.x | c.y | c.z | c.w) & 0x7FFF7FFFu;
        bool occ = (m != 0u);
        size_t vaddr = (size_t)(z0 + oz) * RES2 + (y0 + oy) * RES + xh * 32 + l31;
        const f32x16& acc = oz ? acc1 : acc0;
        #pragma unroll
        for (int r = 0; r < 16; ++r) {
            int o = (r & 3) + 8 * (r >> 2) + 4 * hi;
            float val = occ ? acc[r] : 0.0f;
            out[((size_t)(b * COUT + o) << 18) + vaddr] = val;
        }
    }
}

extern "C" void kernel_launch(void* const* d_in, const int* in_sizes, int n_in,
                              void* d_out, int out_size, void* d_ws, size_t ws_size,
                              hipStream_t stream) {
    const float* x = (const float*)d_in[0];   // [2,16,64,64,64]
    const float* w = (const float*)d_in[1];   // [1,32,16,3,3,3]
    float* out = (float*)d_out;               // [2,32,64,64,64]

    uint4*    xh16 = (uint4*)d_ws;                       // 18.96 MB
    _Float16* wtg  = (_Float16*)((char*)d_ws + WTG_OFF); // 27648 B

    (void)hipFuncSetAttribute(reinterpret_cast<const void*>(conv_kernel),
                              hipFuncAttributeMaxDynamicSharedMemorySize, LDS_BYTES);

    wtrans_kernel<<<(NWH + 255) / 256, 256, 0, stream>>>(w, wtg);
    xcvt_kernel<<<2048, 256, 0, stream>>>(x, xh16);
    conv_kernel<<<1024, 512, LDS_BYTES, stream>>>((const char*)xh16, wtg, out);
}